// Round 18
// baseline (798.224 us; speedup 1.0000x reference)
//
#include <hip/hip_runtime.h>
#include <hip/hip_bf16.h>

typedef __bf16 bf16_t;
typedef __bf16 bf16x8 __attribute__((ext_vector_type(8)));
typedef float  f32x4  __attribute__((ext_vector_type(4)));

#define DM    512
#define NQKV  1536
#define NTOK  65536
#define TM    48          // tokens per tile (3 x 16 m-frags)
#define QSTR  1544        // qkv LDS row stride (elems): 1536 + 8 pad

// Fragment-major repacked weights ("flatmm shuffle"): for wave w (0..7),
// K-step s (0..15), ni (0..11), lane l (0..63), elem e (0..7):
//   ELEM offset = (((w*16+s)*12+ni)*64 + l)*8 + e
//   n = w*192+ni*16+(l&15);  k = s*32+(l>>4)*8+e
// Half-step h: 6 frags at ELEM offset w*98304 + h*3072.
__device__ __align__(16) bf16_t g_wt2[(size_t)NQKV * DM];

#define MEMFENCE asm volatile("" ::: "memory")

typedef const void __attribute__((address_space(1)))* gas_t;
typedef void       __attribute__((address_space(3)))* sas_t;
__device__ __forceinline__ void gl_lds16(const void* g, void* s) {
    __builtin_amdgcn_global_load_lds((gas_t)g, (sas_t)s, 16, 0, 0);
}

// ---------------------------------------------------------------------------
// Kernel 1: scatter W_q|W_k|W_v (fp32 [k][n]) -> g_wt2 fragment-major bf16
// ---------------------------------------------------------------------------
__global__ void prep_w2(const float* __restrict__ Wq,
                        const float* __restrict__ Wk,
                        const float* __restrict__ Wv) {
    int flat = blockIdx.x * 256 + threadIdx.x;   // 0..98303 (one bf16x8 each)
    int l  = flat & 63;
    int kg = l >> 4, lr = l & 15;
    int t2 = flat >> 6;
    int ni = t2 % 12;
    int t3 = t2 / 12;
    int s  = t3 & 15, w = t3 >> 4;
    int n  = w * 192 + ni * 16 + lr;             // 0..1535
    int k0 = s * 32 + kg * 8;
    int mat = n >> 9, nn = n & 511;
    const float* W = (mat == 0) ? Wq : ((mat == 1) ? Wk : Wv);
    bf16x8 v;
#pragma unroll
    for (int e = 0; e < 8; ++e) v[e] = (bf16_t)W[(k0 + e) * DM + nn];
    *(bf16x8*)(g_wt2 + (size_t)flat * 8) = v;
}

// ---------------------------------------------------------------------------
// Kernel 2: PERSISTENT fused QKV projection + cross-head attention.
// Grid 256 (1 block/CU); block b owns 5-6 CONSECUTIVE tiles of 48 tokens.
// Per tile: [A holds x(t)] -> ring prologue -> 32-half-step K-loop (counted
// vmcnt, R10 mechanism) -> barrier -> issue x(t+1) nt-loads into 48 held
// VGPRs (HBM latency hides under attention) -> exchange+attention+stores ->
// vmcnt(0) [drains x-loads AND attention stores so next K-loop's WAITVM(6)
// counts only ring loads] -> ds_write x(t+1) -> next tile.
// This hides the per-generation staging exposure that bounded R11/R17.
// LDS: A [0,48K) | ring [48K,144K) | qkv overlay [0,148224) after K-loop.
// ---------------------------------------------------------------------------
__global__ __launch_bounds__(512, 1) void fused_mha(
    const float* __restrict__ x, float* __restrict__ out, int ntiles) {
    extern __shared__ char sm[];        // 148224 B

    const int tid = threadIdx.x;
    const int l   = tid & 63, w = tid >> 6;
    const int lr  = l & 15,  kg = l >> 4;
    const int rbase = tid >> 5;          // 0..15 (x staging row base)
    const int cj    = tid & 31;          // x staging chunk base

    // ---- persistent tile assignment: consecutive tiles per block -----------
    const int b  = blockIdx.x;                       // 0..255
    const int q  = ntiles >> 8;                      // tiles per block (floor)
    const int r  = ntiles - (q << 8);
    const int t0 = b * q + (b < r ? b : r);
    const int cnt = q + (b < r ? 1 : 0);

    // ---- held-register x staging (12 nt float4 loads / thread) -------------
    f32x4 xr[12];
    auto load_x = [&](size_t tk0, int nt2) {
#pragma unroll
        for (int p = 0; p < 3; ++p)
#pragma unroll
            for (int jj = 0; jj < 2; ++jj) {
                int rr = p * 16 + rbase;
                int c  = cj + jj * 32;
                const float* xp = x + (tk0 + (rr < nt2 ? rr : 0)) * DM + c * 8;
                xr[(p * 2 + jj) * 2 + 0] =
                    __builtin_nontemporal_load((const f32x4*)xp);
                xr[(p * 2 + jj) * 2 + 1] =
                    __builtin_nontemporal_load((const f32x4*)xp + 1);
            }
    };
    auto write_x = [&](int nt2) {      // caller must vmcnt(0) first
#pragma unroll
        for (int p = 0; p < 3; ++p)
#pragma unroll
            for (int jj = 0; jj < 2; ++jj) {
                int rr = p * 16 + rbase;
                int c  = cj + jj * 32;
                f32x4 f0 = xr[(p * 2 + jj) * 2 + 0];
                f32x4 f1 = xr[(p * 2 + jj) * 2 + 1];
                bf16x8 v;
                v[0] = (bf16_t)f0.x; v[1] = (bf16_t)f0.y;
                v[2] = (bf16_t)f0.z; v[3] = (bf16_t)f0.w;
                v[4] = (bf16_t)f1.x; v[5] = (bf16_t)f1.y;
                v[6] = (bf16_t)f1.z; v[7] = (bf16_t)f1.w;
                if (rr >= nt2) {
#pragma unroll
                    for (int e = 0; e < 8; ++e) v[e] = (bf16_t)0.f;
                }
                *(bf16x8*)(sm + rr * 1024 + ((c ^ (rr & 7)) << 4)) = v;
            }
    };

    // ---- B ring: 2 slots x 6144 B per wave at sm+49152 --------------------
    const bf16_t* gwB = g_wt2 + (size_t)w * 98304 + l * 8;   // elem offsets
    char* ringW = sm + 49152 + w * 12288;                     // wave-uniform

#define ISSUE6(h_)                                                            \
    do {                                                                      \
        _Pragma("unroll")                                                     \
        for (int ii = 0; ii < 6; ++ii)                                        \
            gl_lds16(gwB + (size_t)(h_) * 3072 + ii * 512,                    \
                     ringW + ((h_) & 1) * 6144 + ii * 1024);                  \
    } while (0)
#define WAITVM(n_) asm volatile("s_waitcnt vmcnt(" #n_ ")" ::: "memory")

    // ---- prologue: stage x(t0) --------------------------------------------
    if (cnt == 0) return;
    {
        size_t tk0 = (size_t)t0 * TM;
        int ntb0 = (int)((NTOK - tk0) < TM ? (NTOK - tk0) : TM);
        load_x(tk0, ntb0);
        asm volatile("s_waitcnt vmcnt(0)" ::: "memory");
        write_x(ntb0);
        asm volatile("s_waitcnt lgkmcnt(0)" ::: "memory");
        __builtin_amdgcn_s_barrier();
        MEMFENCE;
    }

    const int sx = (lr & 7) << 4;               // A-read swizzle term
    int ntb_cur = (int)((NTOK - (size_t)t0 * TM) < TM
                        ? (NTOK - (size_t)t0 * TM) : TM);

    for (int i = 0; i < cnt; ++i) {
        const int tile = t0 + i;
        const size_t tok0 = (size_t)tile * TM;

        // ---- ring prologue (outstanding VMEM = exactly 12 entering K-loop) -
        ISSUE6(0); ISSUE6(1);

        f32x4 acc[3][12];
#pragma unroll
        for (int a = 0; a < 3; ++a)
#pragma unroll
            for (int bb = 0; bb < 12; ++bb)
                acc[a][bb] = (f32x4){0.f, 0.f, 0.f, 0.f};

        bf16x8 af[3];
#define HSTEP(h_, vm_)                                                        \
    do {                                                                      \
        WAITVM(vm_);                                                          \
        bf16x8 bf_[6];                                                        \
        _Pragma("unroll")                                                     \
        for (int ni = 0; ni < 6; ++ni)                                        \
            bf_[ni] = *(const bf16x8*)(ringW + ((h_) & 1) * 6144 +            \
                                       ni * 1024 + l * 16);                   \
        if (((h_) & 1) == 0) {                                                \
            _Pragma("unroll")                                                 \
            for (int mi = 0; mi < 3; ++mi)                                    \
                af[mi] = *(const bf16x8*)(sm + (mi * 16 + lr) * 1024 +        \
                                          ((((h_) >> 1) * 64 + kg * 16) ^ sx)); \
        }                                                                     \
        asm volatile("s_waitcnt lgkmcnt(0)" ::: "memory");                    \
        __builtin_amdgcn_sched_barrier(0);      /* rule #18 */                \
        if ((h_) + 2 < 32) ISSUE6((h_) + 2);                                  \
        __builtin_amdgcn_s_setprio(1);                                        \
        _Pragma("unroll")                                                     \
        for (int mi = 0; mi < 3; ++mi)                                        \
        _Pragma("unroll")                                                     \
        for (int ni = 0; ni < 6; ++ni)                                        \
            acc[mi][((h_) & 1) * 6 + ni] =                                    \
                __builtin_amdgcn_mfma_f32_16x16x32_bf16(                      \
                    af[mi], bf_[ni], acc[mi][((h_) & 1) * 6 + ni], 0, 0, 0);  \
        __builtin_amdgcn_s_setprio(0);                                        \
    } while (0)

        HSTEP( 0, 6); HSTEP( 1, 6); HSTEP( 2, 6); HSTEP( 3, 6);
        HSTEP( 4, 6); HSTEP( 5, 6); HSTEP( 6, 6); HSTEP( 7, 6);
        HSTEP( 8, 6); HSTEP( 9, 6); HSTEP(10, 6); HSTEP(11, 6);
        HSTEP(12, 6); HSTEP(13, 6); HSTEP(14, 6); HSTEP(15, 6);
        HSTEP(16, 6); HSTEP(17, 6); HSTEP(18, 6); HSTEP(19, 6);
        HSTEP(20, 6); HSTEP(21, 6); HSTEP(22, 6); HSTEP(23, 6);
        HSTEP(24, 6); HSTEP(25, 6); HSTEP(26, 6); HSTEP(27, 6);
        HSTEP(28, 6); HSTEP(29, 6); HSTEP(30, 6); HSTEP(31, 0);
#undef HSTEP

        // ---- everyone done with A + own ring; overlay may begin ------------
        asm volatile("s_waitcnt vmcnt(0) lgkmcnt(0)" ::: "memory");
        __builtin_amdgcn_s_barrier();
        MEMFENCE;

        // ---- issue x(t+1) loads NOW: latency hides under attention ---------
        const int havenext = (i + 1 < cnt);
        int ntb_nxt = TM;
        if (havenext) {
            size_t tkn = tok0 + TM;
            ntb_nxt = (int)((NTOK - tkn) < TM ? (NTOK - tkn) : TM);
            load_x(tkn, ntb_nxt);
        }

        // ---- exchange: acc -> qkv overlay [48][QSTR] -----------------------
        bf16_t* qkv = (bf16_t*)sm;
#pragma unroll
        for (int mi = 0; mi < 3; ++mi)
#pragma unroll
            for (int ni = 0; ni < 12; ++ni) {
                int col = w * 192 + ni * 16 + lr;
#pragma unroll
                for (int ii = 0; ii < 4; ++ii) {
                    int token = mi * 16 + kg * 4 + ii;
                    qkv[token * QSTR + col] = (bf16_t)acc[mi][ni][ii];
                }
            }
        asm volatile("s_waitcnt lgkmcnt(0)" ::: "memory");
        __builtin_amdgcn_s_barrier();
        MEMFENCE;

        // ---- attention: 16 threads/token, two passes (0..31, 32..47) -------
#pragma unroll
        for (int p = 0; p < 2; ++p) {
            const int tok = p * 32 + (tid >> 4);
            if (tok < ntb_cur) {
                const int tj = tid & 15, h = tj & 7, d0 = (tj >> 3) << 5;
                const bf16_t* base = qkv + tok * QSTR;

                float qv[32];
                {
                    const bf16_t* qp = base + h * 64 + d0;
#pragma unroll
                    for (int j = 0; j < 4; ++j) {
                        bf16x8 q8 = *(const bf16x8*)(qp + 8 * j);
#pragma unroll
                        for (int e = 0; e < 8; ++e) qv[8 * j + e] = (float)q8[e];
                    }
                }

                float s[8];
#pragma unroll
                for (int t = 0; t < 8; ++t) {
                    const bf16_t* kp = base + 512 + t * 64 + d0;
                    float a = 0.f;
#pragma unroll
                    for (int j = 0; j < 4; ++j) {
                        bf16x8 k8 = *(const bf16x8*)(kp + 8 * j);
#pragma unroll
                        for (int e = 0; e < 8; ++e) a += qv[8 * j + e] * (float)k8[e];
                    }
                    s[t] = a;
                }
#pragma unroll
                for (int t = 0; t < 8; ++t) s[t] += __shfl_xor(s[t], 8, 64);

                float m = s[0];
#pragma unroll
                for (int t = 1; t < 8; ++t) m = fmaxf(m, s[t]);
                float pr[8], psum = 0.f;
#pragma unroll
                for (int t = 0; t < 8; ++t) {
                    pr[t] = exp2f((s[t] - m) * 1.44269504088896f);
                    psum += pr[t];
                }
                float inv = 1.0f / psum;

                float o[32];
#pragma unroll
                for (int e = 0; e < 32; ++e) o[e] = 0.f;
#pragma unroll
                for (int t = 0; t < 8; ++t) {
                    float pt = pr[t] * inv;
                    const bf16_t* vp = base + 1024 + t * 64 + d0;
#pragma unroll
                    for (int j = 0; j < 4; ++j) {
                        bf16x8 v8 = *(const bf16x8*)(vp + 8 * j);
#pragma unroll
                        for (int e = 0; e < 8; ++e) o[8 * j + e] += pt * (float)v8[e];
                    }
                }

                float* op = out + (tok0 + tok) * DM + h * 64 + d0;
#pragma unroll
                for (int j = 0; j < 8; ++j) {
                    float4 o4 = {o[4*j], o[4*j+1], o[4*j+2], o[4*j+3]};
                    *(float4*)(op + 4 * j) = o4;
                }
            }
        }

        // ---- all attention reads done; drain x-loads + stores --------------
        __builtin_amdgcn_s_barrier();
        MEMFENCE;
        asm volatile("s_waitcnt vmcnt(0)" ::: "memory");
        if (havenext) write_x(ntb_nxt);   // A region: qkv reads complete
        asm volatile("s_waitcnt lgkmcnt(0)" ::: "memory");
        __builtin_amdgcn_s_barrier();
        MEMFENCE;

        ntb_cur = ntb_nxt;
    }
}

// ---------------------------------------------------------------------------
extern "C" void kernel_launch(void* const* d_in, const int* in_sizes, int n_in,
                              void* d_out, int out_size, void* d_ws, size_t ws_size,
                              hipStream_t stream) {
    (void)d_ws; (void)ws_size; (void)n_in; (void)out_size;
    const float* x  = (const float*)d_in[0];
    const float* Wq = (const float*)d_in[1];
    const float* Wk = (const float*)d_in[2];
    const float* Wv = (const float*)d_in[3];
    float* out = (float*)d_out;

    int ntok   = in_sizes[0] / DM;                 // 65536
    int ntiles = (ntok + TM - 1) / TM;             // 1366
    prep_w2<<<384, 256, 0, stream>>>(Wq, Wk, Wv);
    size_t lds = (size_t)TM * QSTR * sizeof(bf16_t);   // 148224 B
    fused_mha<<<256, 512, lds, stream>>>(x, out, ntiles);
}

// Round 19
// 198.759 us; speedup vs baseline: 4.0160x; 4.0160x over previous
//
#include <hip/hip_runtime.h>
#include <hip/hip_bf16.h>

typedef __bf16 bf16_t;
typedef __bf16 bf16x8 __attribute__((ext_vector_type(8)));
typedef float  f32x4  __attribute__((ext_vector_type(4)));

#define DM    512
#define NQKV  1536
#define NTOK  65536
#define TM    48          // tokens per block (3 x 16 m-frags)
#define QSTR  1544        // qkv LDS row stride (elems): 1536 + 8 pad

// Fragment-major repacked weights ("flatmm shuffle"): for wave w (0..7),
// K-step s (0..15), ni (0..11), lane l (0..63), elem e (0..7):
//   ELEM offset = (((w*16+s)*12+ni)*64 + l)*8 + e
//   n = w*192+ni*16+(l&15);  k = s*32+(l>>4)*8+e
// Half-step h (s=h>>1, half=h&1): 6 frags at ELEM offset w*98304 + h*3072
// (= 6144 BYTES per half-step: 6 frags x 64 lanes x 16 B).
__device__ __align__(16) bf16_t g_wt2[(size_t)NQKV * DM];

#define MEMFENCE asm volatile("" ::: "memory")

typedef const void __attribute__((address_space(1)))* gas_t;
typedef void       __attribute__((address_space(3)))* sas_t;
__device__ __forceinline__ void gl_lds16(const void* g, void* s) {
    // async global->LDS, 16B/lane; LDS dest = wave-uniform base + lane*16
    __builtin_amdgcn_global_load_lds((gas_t)g, (sas_t)s, 16, 0, 0);
}

// ---------------------------------------------------------------------------
// Kernel 1: scatter W_q|W_k|W_v (fp32 [k][n]) -> g_wt2 fragment-major bf16
// ---------------------------------------------------------------------------
__global__ void prep_w2(const float* __restrict__ Wq,
                        const float* __restrict__ Wk,
                        const float* __restrict__ Wv) {
    int flat = blockIdx.x * 256 + threadIdx.x;   // 0..98303 (one bf16x8 each)
    int l  = flat & 63;
    int kg = l >> 4, lr = l & 15;
    int t2 = flat >> 6;
    int ni = t2 % 12;
    int t3 = t2 / 12;
    int s  = t3 & 15, w = t3 >> 4;
    int n  = w * 192 + ni * 16 + lr;             // 0..1535
    int k0 = s * 32 + kg * 8;
    int mat = n >> 9, nn = n & 511;
    const float* W = (mat == 0) ? Wq : ((mat == 1) ? Wk : Wv);
    bf16x8 v;
#pragma unroll
    for (int e = 0; e < 8; ++e) v[e] = (bf16_t)W[(k0 + e) * DM + nn];
    *(bf16x8*)(g_wt2 + (size_t)flat * 8) = v;
}

// ---------------------------------------------------------------------------
// Kernel 2: fused QKV projection + cross-head attention (R11, session best).
// 48 tokens/block, 8 waves, 1366 dispatcher-scheduled blocks (generation
// alignment is load-bearing: R18's persistent blocks desynced -> 766 MB of
// HBM weight re-fetch). A (x tile) in LDS [0,48K); B streamed through a
// wave-private 2-slot LDS ring (slot 6144 B) at [48K,144K+3K) via
// global_load_lds + counted vmcnt. Barrier-free K-loop.
// After K-loop: qkv [48][QSTR] (148224 B) overlays from 0 (drain+barrier).
// ---------------------------------------------------------------------------
__global__ __launch_bounds__(512, 1) void fused_mha(
    const float* __restrict__ x, float* __restrict__ out) {
    extern __shared__ char sm[];        // 148224 B

    const int tid = threadIdx.x;
    const int l   = tid & 63, w = tid >> 6;
    const int lr  = l & 15,  kg = l >> 4;
    const size_t tok0 = (size_t)blockIdx.x * TM;
    const int ntb = (int)(((size_t)NTOK - tok0) < TM ? (NTOK - tok0) : TM);

    // ---- stage x tile: fp32 global -> bf16 LDS, 16B-chunk XOR swizzle ------
    {
        const int rbase = tid >> 5;               // 0..15
        const int cj    = tid & 31;
#pragma unroll
        for (int p = 0; p < 3; ++p) {
            int r = p * 16 + rbase;               // 0..47
            int r7 = r & 7;
            if (r < ntb) {
                const float* xp = x + (tok0 + r) * DM;
#pragma unroll
                for (int jj = 0; jj < 2; ++jj) {
                    int c = cj + jj * 32;         // chunk 0..63 (8 bf16 each)
                    float4 f0 = *(const float4*)(xp + c * 8);
                    float4 f1 = *(const float4*)(xp + c * 8 + 4);
                    bf16x8 v;
                    v[0] = (bf16_t)f0.x; v[1] = (bf16_t)f0.y;
                    v[2] = (bf16_t)f0.z; v[3] = (bf16_t)f0.w;
                    v[4] = (bf16_t)f1.x; v[5] = (bf16_t)f1.y;
                    v[6] = (bf16_t)f1.z; v[7] = (bf16_t)f1.w;
                    *(bf16x8*)(sm + r * 1024 + ((c ^ r7) << 4)) = v;
                }
            } else {                               // remainder block: zero rows
                bf16x8 z;
#pragma unroll
                for (int e = 0; e < 8; ++e) z[e] = (bf16_t)0.f;
#pragma unroll
                for (int jj = 0; jj < 2; ++jj) {
                    int c = cj + jj * 32;
                    *(bf16x8*)(sm + r * 1024 + ((c ^ r7) << 4)) = z;
                }
            }
        }
    }

    // ---- B ring: 2 slots x 6144 B per wave at sm+49152 --------------------
    const bf16_t* gwB = g_wt2 + (size_t)w * 98304 + l * 8;   // elem offsets
    char* ringW = sm + 49152 + w * 12288;                     // wave-uniform

#define ISSUE6(h_)                                                            \
    do {                                                                      \
        _Pragma("unroll")                                                     \
        for (int ii = 0; ii < 6; ++ii)                                        \
            gl_lds16(gwB + (size_t)(h_) * 3072 + ii * 512,                    \
                     ringW + ((h_) & 1) * 6144 + ii * 1024);                  \
    } while (0)
#define WAITVM(n_) asm volatile("s_waitcnt vmcnt(" #n_ ")" ::: "memory")

    // prologue: half-steps 0,1 in flight before the staging barrier
    ISSUE6(0); ISSUE6(1);
    asm volatile("s_waitcnt lgkmcnt(0)" ::: "memory");  // x ds_writes drained
    __builtin_amdgcn_s_barrier();
    MEMFENCE;

    // ---- barrier-free K-loop: 32 half-steps, fully unrolled ----------------
    f32x4 acc[3][12];
#pragma unroll
    for (int a = 0; a < 3; ++a)
#pragma unroll
        for (int b = 0; b < 12; ++b) acc[a][b] = (f32x4){0.f, 0.f, 0.f, 0.f};

    const int sx = (lr & 7) << 4;               // A-read swizzle term
    bf16x8 af[3];

#define HSTEP(h_, vm_)                                                        \
    do {                                                                      \
        WAITVM(vm_);              /* slot h_'s 6 stage-loads retired */       \
        bf16x8 bf_[6];                                                        \
        _Pragma("unroll")                                                     \
        for (int ni = 0; ni < 6; ++ni)                                        \
            bf_[ni] = *(const bf16x8*)(ringW + ((h_) & 1) * 6144 +            \
                                       ni * 1024 + l * 16);                   \
        if (((h_) & 1) == 0) {                                                \
            _Pragma("unroll")                                                 \
            for (int mi = 0; mi < 3; ++mi)                                    \
                af[mi] = *(const bf16x8*)(sm + (mi * 16 + lr) * 1024 +        \
                                          ((((h_) >> 1) * 64 + kg * 16) ^ sx)); \
        }                                                                     \
        asm volatile("s_waitcnt lgkmcnt(0)" ::: "memory");                    \
        __builtin_amdgcn_sched_barrier(0);      /* rule #18 */                \
        if ((h_) + 2 < 32) ISSUE6((h_) + 2);    /* refill freed slot */       \
        __builtin_amdgcn_s_setprio(1);                                        \
        _Pragma("unroll")                                                     \
        for (int mi = 0; mi < 3; ++mi)                                        \
        _Pragma("unroll")                                                     \
        for (int ni = 0; ni < 6; ++ni)                                        \
            acc[mi][((h_) & 1) * 6 + ni] =                                    \
                __builtin_amdgcn_mfma_f32_16x16x32_bf16(                      \
                    af[mi], bf_[ni], acc[mi][((h_) & 1) * 6 + ni], 0, 0, 0);  \
        __builtin_amdgcn_s_setprio(0);                                        \
    } while (0)

    HSTEP( 0, 6); HSTEP( 1, 6); HSTEP( 2, 6); HSTEP( 3, 6);
    HSTEP( 4, 6); HSTEP( 5, 6); HSTEP( 6, 6); HSTEP( 7, 6);
    HSTEP( 8, 6); HSTEP( 9, 6); HSTEP(10, 6); HSTEP(11, 6);
    HSTEP(12, 6); HSTEP(13, 6); HSTEP(14, 6); HSTEP(15, 6);
    HSTEP(16, 6); HSTEP(17, 6); HSTEP(18, 6); HSTEP(19, 6);
    HSTEP(20, 6); HSTEP(21, 6); HSTEP(22, 6); HSTEP(23, 6);
    HSTEP(24, 6); HSTEP(25, 6); HSTEP(26, 6); HSTEP(27, 6);
    HSTEP(28, 6); HSTEP(29, 6); HSTEP(30, 6); HSTEP(31, 0);
#undef HSTEP
#undef ISSUE6
#undef WAITVM

    // ---- A + ring dead; full drain + sync before qkv overlays --------------
    asm volatile("s_waitcnt vmcnt(0) lgkmcnt(0)" ::: "memory");
    __builtin_amdgcn_s_barrier();
    MEMFENCE;

    // ---- epilogue: acc -> qkv LDS [48][QSTR] (row = token, col = n) --------
    bf16_t* qkv = (bf16_t*)sm;
#pragma unroll
    for (int mi = 0; mi < 3; ++mi)
#pragma unroll
        for (int ni = 0; ni < 12; ++ni) {
            int col = w * 192 + ni * 16 + lr;
#pragma unroll
            for (int i = 0; i < 4; ++i) {
                int token = mi * 16 + kg * 4 + i;
                qkv[token * QSTR + col] = (bf16_t)acc[mi][ni][i];
            }
        }
    asm volatile("s_waitcnt lgkmcnt(0)" ::: "memory");
    __builtin_amdgcn_s_barrier();
    MEMFENCE;

    // ---- attention: 16 threads/token, two passes (0..31, 32..47) ----------
#pragma unroll
    for (int p = 0; p < 2; ++p) {
        const int tok = p * 32 + (tid >> 4);
        if (tok < ntb) {
            const int tj = tid & 15, h = tj & 7, d0 = (tj >> 3) << 5;
            const bf16_t* base = qkv + tok * QSTR;

            float qv[32];
            {
                const bf16_t* qp = base + h * 64 + d0;
#pragma unroll
                for (int j = 0; j < 4; ++j) {
                    bf16x8 q8 = *(const bf16x8*)(qp + 8 * j);
#pragma unroll
                    for (int e = 0; e < 8; ++e) qv[8 * j + e] = (float)q8[e];
                }
            }

            float s[8];
#pragma unroll
            for (int t = 0; t < 8; ++t) {
                const bf16_t* kp = base + 512 + t * 64 + d0;
                float a = 0.f;
#pragma unroll
                for (int j = 0; j < 4; ++j) {
                    bf16x8 k8 = *(const bf16x8*)(kp + 8 * j);
#pragma unroll
                    for (int e = 0; e < 8; ++e) a += qv[8 * j + e] * (float)k8[e];
                }
                s[t] = a;
            }
            // combine two d-halves (partner lane tid^8: same tok, same h)
#pragma unroll
            for (int t = 0; t < 8; ++t) s[t] += __shfl_xor(s[t], 8, 64);

            float m = s[0];
#pragma unroll
            for (int t = 1; t < 8; ++t) m = fmaxf(m, s[t]);
            float pr[8], psum = 0.f;
#pragma unroll
            for (int t = 0; t < 8; ++t) {
                pr[t] = exp2f((s[t] - m) * 1.44269504088896f);
                psum += pr[t];
            }
            float inv = 1.0f / psum;

            float o[32];
#pragma unroll
            for (int e = 0; e < 32; ++e) o[e] = 0.f;
#pragma unroll
            for (int t = 0; t < 8; ++t) {
                float pt = pr[t] * inv;
                const bf16_t* vp = base + 1024 + t * 64 + d0;
#pragma unroll
                for (int j = 0; j < 4; ++j) {
                    bf16x8 v8 = *(const bf16x8*)(vp + 8 * j);
#pragma unroll
                    for (int e = 0; e < 8; ++e) o[8 * j + e] += pt * (float)v8[e];
                }
            }

            float* op = out + (tok0 + tok) * DM + h * 64 + d0;
#pragma unroll
            for (int j = 0; j < 8; ++j) {
                float4 o4 = {o[4 * j], o[4 * j + 1], o[4 * j + 2], o[4 * j + 3]};
                *(float4*)(op + 4 * j) = o4;
            }
        }
    }
}

// ---------------------------------------------------------------------------
extern "C" void kernel_launch(void* const* d_in, const int* in_sizes, int n_in,
                              void* d_out, int out_size, void* d_ws, size_t ws_size,
                              hipStream_t stream) {
    (void)d_ws; (void)ws_size; (void)n_in; (void)out_size;
    const float* x  = (const float*)d_in[0];
    const float* Wq = (const float*)d_in[1];
    const float* Wk = (const float*)d_in[2];
    const float* Wv = (const float*)d_in[3];
    float* out = (float*)d_out;

    int ntok = in_sizes[0] / DM;                   // 65536
    int grid = (ntok + TM - 1) / TM;               // 1366 (last block: 16 tokens)
    prep_w2<<<384, 256, 0, stream>>>(Wq, Wk, Wv);
    size_t lds = (size_t)TM * QSTR * sizeof(bf16_t);   // 148224 B
    fused_mha<<<grid, 512, lds, stream>>>(x, out);
}